// Round 3
// baseline (754.506 us; speedup 1.0000x reference)
//
#include <hip/hip_runtime.h>

#define N_NODES 100000
#define IN_DIM 128
#define HID 64
#define NUM_GRAPHS 2048
#define CNE_MAX (1600000 + 3 * N_NODES)   // padded-to-4 CSR upper bound
#define BROWS 128                          // rows per bucket
#define NBUCK ((N_NODES + BROWS - 1) / BROWS)   // 782
#define NXCD 8
#define NHIST (NBUCK * NXCD)               // 6256
#define CAP 4096                           // LDS staging entries per bucket (mean ~2240)

// ---------------- degree + (bucket,xcd) histogram ----------------

__global__ void count_hist(const int* __restrict__ dst, int* __restrict__ deg,
                           int* __restrict__ hist, int E) {
    int e = blockIdx.x * 256 + threadIdx.x;
    int vx = blockIdx.x & 7;
    if (e < E) {
        int d = dst[e];
        atomicAdd(&deg[d], 1);
        atomicAdd(&hist[(d >> 7) * NXCD + vx], 1);
    }
}

__global__ void compute_dis(const int* __restrict__ deg, float* __restrict__ dis, int n) {
    int i = blockIdx.x * blockDim.x + threadIdx.x;
    if (i < n) dis[i] = rsqrtf((float)(deg[i] + 1));   // +1 self-loop
}

// ---------------- row_ptr scan (padded-to-4 degrees) ----------------

__global__ void scan1(const int* __restrict__ counts, int* __restrict__ row_ptr1,
                      int* __restrict__ bsum, int n) {
    __shared__ int s[256];
    int t = threadIdx.x;
    int base = blockIdx.x * 1024 + t * 4;
    int v[4];
#pragma unroll
    for (int i = 0; i < 4; i++) {
        int c = (base + i < n) ? counts[base + i] : 0;
        v[i] = (c + 3) & ~3;
    }
    int tsum = v[0] + v[1] + v[2] + v[3];
    s[t] = tsum;
    __syncthreads();
    for (int off = 1; off < 256; off <<= 1) {
        int tv = (t >= off) ? s[t - off] : 0;
        __syncthreads();
        s[t] += tv;
        __syncthreads();
    }
    int excl = s[t] - tsum;
    if (t == 255) bsum[blockIdx.x] = s[255];
    int run = excl;
#pragma unroll
    for (int i = 0; i < 4; i++) {
        run += v[i];
        if (base + i < n) row_ptr1[base + i] = run;
    }
}

__global__ void scan2(const int* __restrict__ bsum, int* __restrict__ boff, int nb) {
    __shared__ int s[128];
    int t = threadIdx.x;
    int v = (t < nb) ? bsum[t] : 0;
    s[t] = v;
    __syncthreads();
    for (int off = 1; off < 128; off <<= 1) {
        int tv = (t >= off) ? s[t - off] : 0;
        __syncthreads();
        s[t] += tv;
        __syncthreads();
    }
    if (t < nb) boff[t] = s[t] - v;
}

__global__ void scan3(int* __restrict__ row_ptr, const int* __restrict__ boff, int n) {
    int i = blockIdx.x * blockDim.x + threadIdx.x;
    if (i == 0) row_ptr[0] = 0;
    if (i < n) row_ptr[i + 1] += boff[i >> 10];
}

// exclusive scan of hist[NHIST] -> part_off (and a working copy in cursor); part_off[NHIST]=E
__global__ void scan_hist(const int* __restrict__ hist, int* __restrict__ part_off,
                          int* __restrict__ cursor) {
    __shared__ int s[256];
    const int CH = (NHIST + 255) / 256;   // 25
    int t = threadIdx.x;
    int base = t * CH;
    int sum = 0;
    for (int i = 0; i < CH; i++)
        if (base + i < NHIST) sum += hist[base + i];
    s[t] = sum;
    __syncthreads();
    for (int off = 1; off < 256; off <<= 1) {
        int v = (t >= off) ? s[t - off] : 0;
        __syncthreads();
        s[t] += v;
        __syncthreads();
    }
    int run = s[t] - sum;
    for (int i = 0; i < CH; i++) {
        if (base + i < NHIST) {
            part_off[base + i] = run;
            cursor[base + i] = run;
            run += hist[base + i];
        }
    }
    if (t == 255) part_off[NHIST] = run;   // == E
}

// partition edges into per-(bucket, virtual-xcd) contiguous strips; 4 B packed entries
__global__ void partition_edges(const int* __restrict__ src, const int* __restrict__ dst,
                                int* __restrict__ cursor, unsigned* __restrict__ part, int E) {
    int e = blockIdx.x * 256 + threadIdx.x;
    int vx = blockIdx.x & 7;
    if (e < E) {
        int s = src[e], d = dst[e];
        int pos = atomicAdd(&cursor[(d >> 7) * NXCD + vx], 1);
        part[pos] = (unsigned)s | ((unsigned)(d & (BROWS - 1)) << 17);
    }
}

// per-bucket CSR build: LDS row cursors + LDS staging, coalesced writeout. Pads -> col N_NODES.
__global__ __launch_bounds__(256) void build_csr(const unsigned* __restrict__ part,
                                                 const int* __restrict__ part_off,
                                                 const int* __restrict__ row_ptr,
                                                 int* __restrict__ cne, int n) {
    __shared__ int fill[BROWS];
    __shared__ int stage[CAP];
    int b = blockIdx.x;
    int r0 = b * BROWS;
    int t = threadIdx.x;
    int nrows = min(BROWS, n - r0);
    int base = row_ptr[r0];
    int region = row_ptr[r0 + nrows] - base;
    for (int r = t; r < nrows; r += 256) fill[r] = row_ptr[r0 + r] - base;
    int i0 = part_off[b * NXCD], i1 = part_off[(b + 1) * NXCD];  // strips are contiguous
    if (region <= CAP) {
        for (int i = t; i < region; i += 256) stage[i] = N_NODES;
        __syncthreads();
        for (int i = i0 + t; i < i1; i += 256) {
            unsigned pe = part[i];
            int pos = atomicAdd(&fill[pe >> 17], 1);
            stage[pos] = (int)(pe & 0x1FFFFu);
        }
        __syncthreads();
        for (int i = t; i < region; i += 256) cne[base + i] = stage[i];
    } else {  // fallback (statistically unreachable), direct global writes
        for (int i = t; i < region; i += 256) cne[base + i] = N_NODES;
        __syncthreads();
        for (int i = i0 + t; i < i1; i += 256) {
            unsigned pe = part[i];
            int pos = atomicAdd(&fill[pe >> 17], 1);
            cne[base + pos] = (int)(pe & 0x1FFFFu);
        }
    }
}

// ---------------- per-layer compute ----------------

__device__ __forceinline__ float bcast(float v, int lane) {
    return __uint_as_float(__builtin_amdgcn_readlane(__float_as_uint(v), lane));
}

// tmp2[row][lane] = dis[row] * sum_k X[row][k] * W[k][lane]; W in registers.
template <int K>
__global__ __launch_bounds__(256) void gemm_rows(const float* __restrict__ X,
                                                 const float* __restrict__ W,
                                                 const float* __restrict__ dis,
                                                 float* __restrict__ out, int n) {
    int wave = threadIdx.x >> 6, lane = threadIdx.x & 63;
    float w[K];
#pragma unroll
    for (int k = 0; k < K; k++) w[k] = W[k * HID + lane];
    int wpb = blockDim.x >> 6;
    int stride = gridDim.x * wpb;
    for (int row = blockIdx.x * wpb + wave; row < n; row += stride) {
        const float* xr = X + (size_t)row * K;
        float acc0 = 0.f, acc1 = 0.f;
        float xv0 = xr[lane];
        if constexpr (K == 128) {
            float xv1 = xr[lane + 64];
#pragma unroll
            for (int k = 0; k < 64; k += 2) {
                acc0 += bcast(xv0, k) * w[k];
                acc1 += bcast(xv0, k + 1) * w[k + 1];
            }
#pragma unroll
            for (int k = 0; k < 64; k += 2) {
                acc0 += bcast(xv1, k) * w[k + 64];
                acc1 += bcast(xv1, k + 1) * w[k + 65];
            }
        } else {
#pragma unroll
            for (int k = 0; k < 64; k += 2) {
                acc0 += bcast(xv0, k) * w[k];
                acc1 += bcast(xv0, k + 1) * w[k + 1];
            }
        }
        out[(size_t)row * HID + lane] = dis[row] * (acc0 + acc1);
    }
}

// out[row] = relu( dis[row] * (tmp2[row] + sum_cols tmp2[col]) + bias ); pads read zero row N.
__global__ __launch_bounds__(256) void aggregate(const float* __restrict__ tmp,
                                                 const float* __restrict__ dis,
                                                 const int* __restrict__ row_ptr,
                                                 const int* __restrict__ cne,
                                                 const float* __restrict__ bias,
                                                 float* __restrict__ out, int n) {
    int wave = threadIdx.x >> 6, lane = threadIdx.x & 63;
    int wpb = blockDim.x >> 6;
    int stride = gridDim.x * wpb;
    float bl = bias[lane];
    for (int row = blockIdx.x * wpb + wave; row < n; row += stride) {
        float dr = dis[row];
        float acc0 = tmp[(size_t)row * HID + lane];   // self-loop (tmp2 already has dis[src])
        float acc1 = 0.f, acc2 = 0.f, acc3 = 0.f;
        int s = row_ptr[row], e = row_ptr[row + 1];
        if (s < e) {
            int4 c = *(const int4*)(cne + s);
            float v0 = tmp[(size_t)c.x * HID + lane];
            float v1 = tmp[(size_t)c.y * HID + lane];
            float v2 = tmp[(size_t)c.z * HID + lane];
            float v3 = tmp[(size_t)c.w * HID + lane];
            for (int t = s + 4; t < e; t += 4) {
                int4 d4 = *(const int4*)(cne + t);
                float u0 = tmp[(size_t)d4.x * HID + lane];
                float u1 = tmp[(size_t)d4.y * HID + lane];
                float u2 = tmp[(size_t)d4.z * HID + lane];
                float u3 = tmp[(size_t)d4.w * HID + lane];
                acc0 += v0; acc1 += v1; acc2 += v2; acc3 += v3;
                c = d4;
                v0 = u0; v1 = u1; v2 = u2; v3 = u3;
            }
            acc0 += v0; acc1 += v1; acc2 += v2; acc3 += v3;
        }
        float r = dr * ((acc0 + acc1) + (acc2 + acc3)) + bl;
        out[(size_t)row * HID + lane] = fmaxf(r, 0.f);
    }
}

// one block (4 waves) per graph: mean+max pool, fused output dot
__global__ __launch_bounds__(256) void pool_kernel(const float* __restrict__ h,
                                                   const int* __restrict__ batch,
                                                   const float* __restrict__ Wout,
                                                   const float* __restrict__ bout,
                                                   float* __restrict__ d_out, int n) {
    __shared__ float ssum[4][64];
    __shared__ float smax[4][64];
    int g = blockIdx.x;
    int wave = threadIdx.x >> 6, j = threadIdx.x & 63;
    int lo = 0, hi = n;
    while (lo < hi) { int mid = (lo + hi) >> 1; if (batch[mid] < g) lo = mid + 1; else hi = mid; }
    int start = lo;
    hi = n;
    while (lo < hi) { int mid = (lo + hi) >> 1; if (batch[mid] < g + 1) lo = mid + 1; else hi = mid; }
    int end = lo;

    float sum = 0.f, mx = 0.f;   // h >= 0 post-relu; empty graph -> 0 per reference
    for (int i = start + wave; i < end; i += 4) {
        float v = h[(size_t)i * HID + j];
        sum += v;
        mx = fmaxf(mx, v);
    }
    ssum[wave][j] = sum;
    smax[wave][j] = mx;
    __syncthreads();
    if (wave == 0) {
        sum = (ssum[0][j] + ssum[1][j]) + (ssum[2][j] + ssum[3][j]);
        mx = fmaxf(fmaxf(smax[0][j], smax[1][j]), fmaxf(smax[2][j], smax[3][j]));
        float cnt = (float)(end - start);
        float mean = sum / fmaxf(cnt, 1.f);
        float* pooled = d_out + NUM_GRAPHS;
        pooled[(size_t)g * (2 * HID) + j] = mean;
        pooled[(size_t)g * (2 * HID) + HID + j] = mx;
        float c = mean * Wout[j] + mx * Wout[HID + j];
#pragma unroll
        for (int off = 32; off; off >>= 1) c += __shfl_down(c, off);
        if (j == 0) d_out[g] = c + bout[0];
    }
}

// ---------------- launch ----------------

extern "C" void kernel_launch(void* const* d_in, const int* in_sizes, int n_in,
                              void* d_out, int out_size, void* d_ws, size_t ws_size,
                              hipStream_t stream) {
    const float* x    = (const float*)d_in[0];
    const int*   edge = (const int*)d_in[1];
    const int*   batch= (const int*)d_in[2];
    const float* W1 = (const float*)d_in[3];  const float* b1 = (const float*)d_in[4];
    const float* W2 = (const float*)d_in[5];  const float* b2 = (const float*)d_in[6];
    const float* W3 = (const float*)d_in[7];  const float* b3 = (const float*)d_in[8];
    const float* W4 = (const float*)d_in[9];  const float* b4 = (const float*)d_in[10];
    const float* Wout = (const float*)d_in[11]; const float* bout = (const float*)d_in[12];
    float* out = (float*)d_out;

    const int N = N_NODES;
    const int E = in_sizes[1] / 2;
    const int* src = edge;
    const int* dst = edge + E;

    char* p = (char*)d_ws;
    auto alloc = [&](size_t bytes) -> char* {
        char* r = p;
        p += (bytes + 255) & ~(size_t)255;
        return r;
    };
    int*      deg      = (int*)alloc((size_t)N * 4);
    int*      row_ptr  = (int*)alloc((size_t)(N + 1) * 4);
    int*      hist     = (int*)alloc((size_t)NHIST * 4);
    int*      part_off = (int*)alloc((size_t)(NHIST + 1) * 4);
    int*      cursor   = (int*)alloc((size_t)NHIST * 4);
    unsigned* part     = (unsigned*)alloc((size_t)1600000 * 4);
    int*      cne      = (int*)alloc((size_t)CNE_MAX * 4);
    float*    dis      = (float*)alloc((size_t)N * 4);
    int*      bsum     = (int*)alloc(128 * 4);
    int*      boff     = (int*)alloc(128 * 4);
    float*    tmp      = (float*)alloc((size_t)(N + 1) * HID * 4);
    float*    hA       = (float*)alloc((size_t)(N + 1) * HID * 4);

    hipMemsetAsync(deg, 0, (size_t)N * 4, stream);
    hipMemsetAsync(hist, 0, (size_t)NHIST * 4, stream);
    hipMemsetAsync(tmp + (size_t)N * HID, 0, HID * 4, stream);   // zero row N (pad target)
    hipMemsetAsync(hA + (size_t)N * HID, 0, HID * 4, stream);

    int eb = (E + 255) / 256;
    count_hist<<<eb, 256, 0, stream>>>(dst, deg, hist, E);
    compute_dis<<<(N + 255) / 256, 256, 0, stream>>>(deg, dis, N);

    int nb = (N + 1023) / 1024;  // 98
    scan1<<<nb, 256, 0, stream>>>(deg, row_ptr + 1, bsum, N);
    scan2<<<1, 128, 0, stream>>>(bsum, boff, nb);
    scan3<<<(N + 255) / 256, 256, 0, stream>>>(row_ptr, boff, N);
    scan_hist<<<1, 256, 0, stream>>>(hist, part_off, cursor);
    partition_edges<<<eb, 256, 0, stream>>>(src, dst, cursor, part, E);
    build_csr<<<NBUCK, 256, 0, stream>>>(part, part_off, row_ptr, cne, N);

    const int AGG_BLOCKS = 2048;

    gemm_rows<IN_DIM><<<1024, 256, 0, stream>>>(x, W1, dis, tmp, N);
    aggregate<<<AGG_BLOCKS, 256, 0, stream>>>(tmp, dis, row_ptr, cne, b1, hA, N);
    gemm_rows<HID><<<2048, 256, 0, stream>>>(hA, W2, dis, tmp, N);
    aggregate<<<AGG_BLOCKS, 256, 0, stream>>>(tmp, dis, row_ptr, cne, b2, hA, N);
    gemm_rows<HID><<<2048, 256, 0, stream>>>(hA, W3, dis, tmp, N);
    aggregate<<<AGG_BLOCKS, 256, 0, stream>>>(tmp, dis, row_ptr, cne, b3, hA, N);
    gemm_rows<HID><<<2048, 256, 0, stream>>>(hA, W4, dis, tmp, N);
    aggregate<<<AGG_BLOCKS, 256, 0, stream>>>(tmp, dis, row_ptr, cne, b4, hA, N);

    pool_kernel<<<NUM_GRAPHS, 256, 0, stream>>>(hA, batch, Wout, bout, out, N);
}

// Round 4
// 661.448 us; speedup vs baseline: 1.1407x; 1.1407x over previous
//
#include <hip/hip_runtime.h>

#define N_NODES 100000
#define IN_DIM 128
#define HID 64
#define NUM_GRAPHS 2048
#define CNE_MAX (1600000 + 3 * N_NODES)   // padded-to-4 CSR upper bound
#define BROWS 128                          // rows per bucket
#define NBUCK ((N_NODES + BROWS - 1) / BROWS)   // 782
#define NCHUNK 64                          // edge chunks (one block each)
#define TOTP (NBUCK * NCHUNK)              // 50048 partial counters
#define CAP 4096                           // LDS staging entries per bucket (mean ~2240)

// ---------------- build phase (NO per-edge global atomics anywhere) ----------------

// per-chunk bucket histogram in LDS -> partial[bucket][chunk] (bucket-major)
__global__ __launch_bounds__(256) void hist_partial(const int* __restrict__ dst,
                                                    int* __restrict__ partial,
                                                    int E, int chunk) {
    __shared__ int lh[NBUCK];
    int t = threadIdx.x, c = blockIdx.x;
    for (int b = t; b < NBUCK; b += 256) lh[b] = 0;
    __syncthreads();
    int lo = c * chunk, hi = min(lo + chunk, E);
    for (int i = lo + t; i < hi; i += 256) atomicAdd(&lh[dst[i] >> 7], 1);
    __syncthreads();
    for (int b = t; b < NBUCK; b += 256) partial[b * NCHUNK + c] = lh[b];
}

// exclusive scan of partial (bucket-major) -> base (same layout) + part_off[b] = base[b][0]
__global__ __launch_bounds__(256) void scan_part(const int* __restrict__ partial,
                                                 int* __restrict__ base,
                                                 int* __restrict__ part_off, int E) {
    __shared__ int s[256];
    const int CH = (TOTP + 255) / 256;   // 196
    int t = threadIdx.x;
    int lo = t * CH, hi = min(lo + CH, TOTP);
    int sum = 0;
    for (int i = lo; i < hi; i++) sum += partial[i];
    s[t] = sum;
    __syncthreads();
    for (int off = 1; off < 256; off <<= 1) {
        int v = (t >= off) ? s[t - off] : 0;
        __syncthreads();
        s[t] += v;
        __syncthreads();
    }
    int run = s[t] - sum;
    for (int i = lo; i < hi; i++) {
        base[i] = run;
        run += partial[i];
    }
    __syncthreads();
    for (int b = t; b <= NBUCK; b += 256)
        part_off[b] = (b < NBUCK) ? base[b * NCHUNK] : E;
}

// stable partition: each chunk re-reads its edges, takes positions from LDS cursors
__global__ __launch_bounds__(256) void partition_edges(const int* __restrict__ src,
                                                       const int* __restrict__ dst,
                                                       const int* __restrict__ base,
                                                       unsigned* __restrict__ part,
                                                       int E, int chunk) {
    __shared__ int cur[NBUCK];
    int t = threadIdx.x, c = blockIdx.x;
    for (int b = t; b < NBUCK; b += 256) cur[b] = base[b * NCHUNK + c];
    __syncthreads();
    int lo = c * chunk, hi = min(lo + chunk, E);
    for (int i = lo + t; i < hi; i += 256) {
        int s = src[i], d = dst[i];
        int pos = atomicAdd(&cur[d >> 7], 1);
        part[pos] = (unsigned)s | ((unsigned)(d & (BROWS - 1)) << 17);
    }
}

// per-bucket local-row counts from the strip -> padded degree + dis, coalesced writes
__global__ __launch_bounds__(256) void deg_dis(const unsigned* __restrict__ part,
                                               const int* __restrict__ part_off,
                                               int* __restrict__ pdeg,
                                               float* __restrict__ dis, int n) {
    __shared__ int cnt[BROWS];
    int t = threadIdx.x, b = blockIdx.x;
    int r0 = b * BROWS;
    if (t < BROWS) cnt[t] = 0;
    __syncthreads();
    for (int i = part_off[b] + t; i < part_off[b + 1]; i += 256)
        atomicAdd(&cnt[part[i] >> 17], 1);
    __syncthreads();
    int nrows = min(BROWS, n - r0);
    if (t < nrows) {
        int dg = cnt[t];
        pdeg[r0 + t] = (dg + 3) & ~3;               // pad row segment to multiple of 4
        dis[r0 + t] = rsqrtf((float)(dg + 1));      // +1 self-loop
    }
}

// ---------------- row_ptr scan (over already-padded degrees) ----------------

__global__ void scan1(const int* __restrict__ counts, int* __restrict__ row_ptr1,
                      int* __restrict__ bsum, int n) {
    __shared__ int s[256];
    int t = threadIdx.x;
    int base = blockIdx.x * 1024 + t * 4;
    int v[4];
#pragma unroll
    for (int i = 0; i < 4; i++) v[i] = (base + i < n) ? counts[base + i] : 0;
    int tsum = v[0] + v[1] + v[2] + v[3];
    s[t] = tsum;
    __syncthreads();
    for (int off = 1; off < 256; off <<= 1) {
        int tv = (t >= off) ? s[t - off] : 0;
        __syncthreads();
        s[t] += tv;
        __syncthreads();
    }
    int excl = s[t] - tsum;
    if (t == 255) bsum[blockIdx.x] = s[255];
    int run = excl;
#pragma unroll
    for (int i = 0; i < 4; i++) {
        run += v[i];
        if (base + i < n) row_ptr1[base + i] = run;
    }
}

__global__ void scan2(const int* __restrict__ bsum, int* __restrict__ boff, int nb) {
    __shared__ int s[128];
    int t = threadIdx.x;
    int v = (t < nb) ? bsum[t] : 0;
    s[t] = v;
    __syncthreads();
    for (int off = 1; off < 128; off <<= 1) {
        int tv = (t >= off) ? s[t - off] : 0;
        __syncthreads();
        s[t] += tv;
        __syncthreads();
    }
    if (t < nb) boff[t] = s[t] - v;
}

__global__ void scan3(int* __restrict__ row_ptr, const int* __restrict__ boff, int n) {
    int i = blockIdx.x * blockDim.x + threadIdx.x;
    if (i == 0) row_ptr[0] = 0;
    if (i < n) row_ptr[i + 1] += boff[i >> 10];
}

// per-bucket CSR build: LDS row cursors + LDS staging, coalesced writeout. Pads -> col N_NODES.
__global__ __launch_bounds__(256) void build_csr(const unsigned* __restrict__ part,
                                                 const int* __restrict__ part_off,
                                                 const int* __restrict__ row_ptr,
                                                 int* __restrict__ cne, int n) {
    __shared__ int fill[BROWS];
    __shared__ int stage[CAP];
    int b = blockIdx.x;
    int r0 = b * BROWS;
    int t = threadIdx.x;
    int nrows = min(BROWS, n - r0);
    int base = row_ptr[r0];
    int region = row_ptr[r0 + nrows] - base;
    for (int r = t; r < nrows; r += 256) fill[r] = row_ptr[r0 + r] - base;
    int i0 = part_off[b], i1 = part_off[b + 1];
    if (region <= CAP) {
        for (int i = t; i < region; i += 256) stage[i] = N_NODES;
        __syncthreads();
        for (int i = i0 + t; i < i1; i += 256) {
            unsigned pe = part[i];
            int pos = atomicAdd(&fill[pe >> 17], 1);
            stage[pos] = (int)(pe & 0x1FFFFu);
        }
        __syncthreads();
        for (int i = t; i < region; i += 256) cne[base + i] = stage[i];
    } else {  // fallback (statistically unreachable)
        for (int i = t; i < region; i += 256) cne[base + i] = N_NODES;
        __syncthreads();
        for (int i = i0 + t; i < i1; i += 256) {
            unsigned pe = part[i];
            int pos = atomicAdd(&fill[pe >> 17], 1);
            cne[base + pos] = (int)(pe & 0x1FFFFu);
        }
    }
}

// ---------------- per-layer compute ----------------

__device__ __forceinline__ float bcast(float v, int lane) {
    return __uint_as_float(__builtin_amdgcn_readlane(__float_as_uint(v), lane));
}

// tmp2[row][lane] = dis[row] * sum_k X[row][k] * W[k][lane]; W in registers.
template <int K>
__global__ __launch_bounds__(256) void gemm_rows(const float* __restrict__ X,
                                                 const float* __restrict__ W,
                                                 const float* __restrict__ dis,
                                                 float* __restrict__ out, int n) {
    int wave = threadIdx.x >> 6, lane = threadIdx.x & 63;
    float w[K];
#pragma unroll
    for (int k = 0; k < K; k++) w[k] = W[k * HID + lane];
    int wpb = blockDim.x >> 6;
    int stride = gridDim.x * wpb;
    for (int row = blockIdx.x * wpb + wave; row < n; row += stride) {
        const float* xr = X + (size_t)row * K;
        float acc0 = 0.f, acc1 = 0.f;
        float xv0 = xr[lane];
        if constexpr (K == 128) {
            float xv1 = xr[lane + 64];
#pragma unroll
            for (int k = 0; k < 64; k += 2) {
                acc0 += bcast(xv0, k) * w[k];
                acc1 += bcast(xv0, k + 1) * w[k + 1];
            }
#pragma unroll
            for (int k = 0; k < 64; k += 2) {
                acc0 += bcast(xv1, k) * w[k + 64];
                acc1 += bcast(xv1, k + 1) * w[k + 65];
            }
        } else {
#pragma unroll
            for (int k = 0; k < 64; k += 2) {
                acc0 += bcast(xv0, k) * w[k];
                acc1 += bcast(xv0, k + 1) * w[k + 1];
            }
        }
        out[(size_t)row * HID + lane] = dis[row] * (acc0 + acc1);
    }
}

// out[row] = relu( dis[row] * (tmp2[row] + sum_cols tmp2[col]) + bias ); pads read zero row N.
__global__ __launch_bounds__(256) void aggregate(const float* __restrict__ tmp,
                                                 const float* __restrict__ dis,
                                                 const int* __restrict__ row_ptr,
                                                 const int* __restrict__ cne,
                                                 const float* __restrict__ bias,
                                                 float* __restrict__ out, int n) {
    int wave = threadIdx.x >> 6, lane = threadIdx.x & 63;
    int wpb = blockDim.x >> 6;
    int stride = gridDim.x * wpb;
    float bl = bias[lane];
    for (int row = blockIdx.x * wpb + wave; row < n; row += stride) {
        float dr = dis[row];
        float acc0 = tmp[(size_t)row * HID + lane];   // self-loop (tmp2 already has dis[src])
        float acc1 = 0.f, acc2 = 0.f, acc3 = 0.f;
        int s = row_ptr[row], e = row_ptr[row + 1];
        if (s < e) {
            int4 c = *(const int4*)(cne + s);
            float v0 = tmp[(size_t)c.x * HID + lane];
            float v1 = tmp[(size_t)c.y * HID + lane];
            float v2 = tmp[(size_t)c.z * HID + lane];
            float v3 = tmp[(size_t)c.w * HID + lane];
            for (int t = s + 4; t < e; t += 4) {
                int4 d4 = *(const int4*)(cne + t);
                float u0 = tmp[(size_t)d4.x * HID + lane];
                float u1 = tmp[(size_t)d4.y * HID + lane];
                float u2 = tmp[(size_t)d4.z * HID + lane];
                float u3 = tmp[(size_t)d4.w * HID + lane];
                acc0 += v0; acc1 += v1; acc2 += v2; acc3 += v3;
                c = d4;
                v0 = u0; v1 = u1; v2 = u2; v3 = u3;
            }
            acc0 += v0; acc1 += v1; acc2 += v2; acc3 += v3;
        }
        float r = dr * ((acc0 + acc1) + (acc2 + acc3)) + bl;
        out[(size_t)row * HID + lane] = fmaxf(r, 0.f);
    }
}

// one block (4 waves) per graph: mean+max pool, fused output dot
__global__ __launch_bounds__(256) void pool_kernel(const float* __restrict__ h,
                                                   const int* __restrict__ batch,
                                                   const float* __restrict__ Wout,
                                                   const float* __restrict__ bout,
                                                   float* __restrict__ d_out, int n) {
    __shared__ float ssum[4][64];
    __shared__ float smax[4][64];
    int g = blockIdx.x;
    int wave = threadIdx.x >> 6, j = threadIdx.x & 63;
    int lo = 0, hi = n;
    while (lo < hi) { int mid = (lo + hi) >> 1; if (batch[mid] < g) lo = mid + 1; else hi = mid; }
    int start = lo;
    hi = n;
    while (lo < hi) { int mid = (lo + hi) >> 1; if (batch[mid] < g + 1) lo = mid + 1; else hi = mid; }
    int end = lo;

    float sum = 0.f, mx = 0.f;   // h >= 0 post-relu; empty graph -> 0 per reference
    for (int i = start + wave; i < end; i += 4) {
        float v = h[(size_t)i * HID + j];
        sum += v;
        mx = fmaxf(mx, v);
    }
    ssum[wave][j] = sum;
    smax[wave][j] = mx;
    __syncthreads();
    if (wave == 0) {
        sum = (ssum[0][j] + ssum[1][j]) + (ssum[2][j] + ssum[3][j]);
        mx = fmaxf(fmaxf(smax[0][j], smax[1][j]), fmaxf(smax[2][j], smax[3][j]));
        float cnt = (float)(end - start);
        float mean = sum / fmaxf(cnt, 1.f);
        float* pooled = d_out + NUM_GRAPHS;
        pooled[(size_t)g * (2 * HID) + j] = mean;
        pooled[(size_t)g * (2 * HID) + HID + j] = mx;
        float c = mean * Wout[j] + mx * Wout[HID + j];
#pragma unroll
        for (int off = 32; off; off >>= 1) c += __shfl_down(c, off);
        if (j == 0) d_out[g] = c + bout[0];
    }
}

// ---------------- launch ----------------

extern "C" void kernel_launch(void* const* d_in, const int* in_sizes, int n_in,
                              void* d_out, int out_size, void* d_ws, size_t ws_size,
                              hipStream_t stream) {
    const float* x    = (const float*)d_in[0];
    const int*   edge = (const int*)d_in[1];
    const int*   batch= (const int*)d_in[2];
    const float* W1 = (const float*)d_in[3];  const float* b1 = (const float*)d_in[4];
    const float* W2 = (const float*)d_in[5];  const float* b2 = (const float*)d_in[6];
    const float* W3 = (const float*)d_in[7];  const float* b3 = (const float*)d_in[8];
    const float* W4 = (const float*)d_in[9];  const float* b4 = (const float*)d_in[10];
    const float* Wout = (const float*)d_in[11]; const float* bout = (const float*)d_in[12];
    float* out = (float*)d_out;

    const int N = N_NODES;
    const int E = in_sizes[1] / 2;
    const int* src = edge;
    const int* dst = edge + E;
    const int chunk = (E + NCHUNK - 1) / NCHUNK;

    char* p = (char*)d_ws;
    auto alloc = [&](size_t bytes) -> char* {
        char* r = p;
        p += (bytes + 255) & ~(size_t)255;
        return r;
    };
    int*      pdeg     = (int*)alloc((size_t)N * 4);
    int*      row_ptr  = (int*)alloc((size_t)(N + 1) * 4);
    int*      partial  = (int*)alloc((size_t)TOTP * 4);
    int*      pbase    = (int*)alloc((size_t)TOTP * 4);
    int*      part_off = (int*)alloc((size_t)(NBUCK + 1) * 4);
    unsigned* part     = (unsigned*)alloc((size_t)1600000 * 4);
    int*      cne      = (int*)alloc((size_t)CNE_MAX * 4);
    float*    dis      = (float*)alloc((size_t)N * 4);
    int*      bsum     = (int*)alloc(128 * 4);
    int*      boff     = (int*)alloc(128 * 4);
    float*    tmp      = (float*)alloc((size_t)(N + 1) * HID * 4);
    float*    hA       = (float*)alloc((size_t)(N + 1) * HID * 4);

    hipMemsetAsync(tmp + (size_t)N * HID, 0, HID * 4, stream);   // zero row N (pad target)
    hipMemsetAsync(hA + (size_t)N * HID, 0, HID * 4, stream);

    hist_partial<<<NCHUNK, 256, 0, stream>>>(dst, partial, E, chunk);
    scan_part<<<1, 256, 0, stream>>>(partial, pbase, part_off, E);
    partition_edges<<<NCHUNK, 256, 0, stream>>>(src, dst, pbase, part, E, chunk);
    deg_dis<<<NBUCK, 256, 0, stream>>>(part, part_off, pdeg, dis, N);

    int nb = (N + 1023) / 1024;  // 98
    scan1<<<nb, 256, 0, stream>>>(pdeg, row_ptr + 1, bsum, N);
    scan2<<<1, 128, 0, stream>>>(bsum, boff, nb);
    scan3<<<(N + 255) / 256, 256, 0, stream>>>(row_ptr, boff, N);
    build_csr<<<NBUCK, 256, 0, stream>>>(part, part_off, row_ptr, cne, N);

    const int AGG_BLOCKS = 2048;

    gemm_rows<IN_DIM><<<1024, 256, 0, stream>>>(x, W1, dis, tmp, N);
    aggregate<<<AGG_BLOCKS, 256, 0, stream>>>(tmp, dis, row_ptr, cne, b1, hA, N);
    gemm_rows<HID><<<2048, 256, 0, stream>>>(hA, W2, dis, tmp, N);
    aggregate<<<AGG_BLOCKS, 256, 0, stream>>>(tmp, dis, row_ptr, cne, b2, hA, N);
    gemm_rows<HID><<<2048, 256, 0, stream>>>(hA, W3, dis, tmp, N);
    aggregate<<<AGG_BLOCKS, 256, 0, stream>>>(tmp, dis, row_ptr, cne, b3, hA, N);
    gemm_rows<HID><<<2048, 256, 0, stream>>>(hA, W4, dis, tmp, N);
    aggregate<<<AGG_BLOCKS, 256, 0, stream>>>(tmp, dis, row_ptr, cne, b4, hA, N);

    pool_kernel<<<NUM_GRAPHS, 256, 0, stream>>>(hA, batch, Wout, bout, out, N);
}

// Round 5
// 561.463 us; speedup vs baseline: 1.3438x; 1.1781x over previous
//
#include <hip/hip_runtime.h>

#define N_NODES 100000
#define IN_DIM 128
#define HID 64
#define NUM_GRAPHS 2048
#define CNE_MAX (1600000 + 3 * N_NODES)   // padded-to-4 CSR upper bound
#define BROWS 128                          // rows per bucket
#define NBUCK ((N_NODES + BROWS - 1) / BROWS)   // 782
#define NCHUNK 128                         // edge chunks (one block each)
#define TOTP (NBUCK * NCHUNK)              // 100096 partial counters
#define CAP 4096                           // LDS staging entries per bucket (mean ~2240)

// ---------------- build phase (NO per-edge global atomics anywhere) ----------------

// per-chunk bucket histogram in LDS -> partial[bucket][chunk] (bucket-major)
__global__ __launch_bounds__(256) void hist_partial(const int* __restrict__ dst,
                                                    int* __restrict__ partial,
                                                    int E, int chunk) {
    __shared__ int lh[NBUCK];
    int t = threadIdx.x, c = blockIdx.x;
    for (int b = t; b < NBUCK; b += 256) lh[b] = 0;
    __syncthreads();
    int lo = c * chunk, hi = min(lo + chunk, E);
    for (int i = lo + t; i < hi; i += 256) atomicAdd(&lh[dst[i] >> 7], 1);
    __syncthreads();
    for (int b = t; b < NBUCK; b += 256) partial[b * NCHUNK + c] = lh[b];
}

// generic hierarchical scan, phase 1: per-block (1024 elems) inclusive scan + block sums
__global__ void scan1(const int* __restrict__ counts, int* __restrict__ out1,
                      int* __restrict__ bsum, int n) {
    __shared__ int s[256];
    int t = threadIdx.x;
    int base = blockIdx.x * 1024 + t * 4;
    int v[4];
#pragma unroll
    for (int i = 0; i < 4; i++) v[i] = (base + i < n) ? counts[base + i] : 0;
    int tsum = v[0] + v[1] + v[2] + v[3];
    s[t] = tsum;
    __syncthreads();
    for (int off = 1; off < 256; off <<= 1) {
        int tv = (t >= off) ? s[t - off] : 0;
        __syncthreads();
        s[t] += tv;
        __syncthreads();
    }
    int excl = s[t] - tsum;
    if (t == 255) bsum[blockIdx.x] = s[255];
    int run = excl;
#pragma unroll
    for (int i = 0; i < 4; i++) {
        run += v[i];
        if (base + i < n) out1[base + i] = run;
    }
}

// phase 2: exclusive scan of block sums (nb <= 128)
__global__ void scan2(const int* __restrict__ bsum, int* __restrict__ boff, int nb) {
    __shared__ int s[128];
    int t = threadIdx.x;
    int v = (t < nb) ? bsum[t] : 0;
    s[t] = v;
    __syncthreads();
    for (int off = 1; off < 128; off <<= 1) {
        int tv = (t >= off) ? s[t - off] : 0;
        __syncthreads();
        s[t] += tv;
        __syncthreads();
    }
    if (t < nb) boff[t] = s[t] - v;
}

// phase 3 for row_ptr: add block offsets in place
__global__ void scan3(int* __restrict__ row_ptr, const int* __restrict__ boff, int n) {
    int i = blockIdx.x * blockDim.x + threadIdx.x;
    if (i == 0) row_ptr[0] = 0;
    if (i < n) row_ptr[i + 1] += boff[i >> 10];
}

// phase 3 for partial: exclusive = inclusive - self + block_off; emit part_off per bucket
__global__ void scan3p(const int* __restrict__ partial, const int* __restrict__ pincl,
                       const int* __restrict__ boff, int* __restrict__ base,
                       int* __restrict__ part_off, int E) {
    int i = blockIdx.x * blockDim.x + threadIdx.x;
    if (i < TOTP) {
        int v = pincl[i] + boff[i >> 10] - partial[i];
        base[i] = v;
        if ((i & (NCHUNK - 1)) == 0) part_off[i / NCHUNK] = v;
    }
    if (i == 0) part_off[NBUCK] = E;
}

// stable partition: each chunk re-reads its edges, takes positions from LDS cursors
__global__ __launch_bounds__(256) void partition_edges(const int* __restrict__ src,
                                                       const int* __restrict__ dst,
                                                       const int* __restrict__ base,
                                                       unsigned* __restrict__ part,
                                                       int E, int chunk) {
    __shared__ int cur[NBUCK];
    int t = threadIdx.x, c = blockIdx.x;
    for (int b = t; b < NBUCK; b += 256) cur[b] = base[b * NCHUNK + c];
    __syncthreads();
    int lo = c * chunk, hi = min(lo + chunk, E);
    for (int i = lo + t; i < hi; i += 256) {
        int s = src[i], d = dst[i];
        int pos = atomicAdd(&cur[d >> 7], 1);
        part[pos] = (unsigned)s | ((unsigned)(d & (BROWS - 1)) << 17);
    }
}

// per-bucket local-row counts from the strip -> padded degree + dis, coalesced writes
__global__ __launch_bounds__(256) void deg_dis(const unsigned* __restrict__ part,
                                               const int* __restrict__ part_off,
                                               int* __restrict__ pdeg,
                                               float* __restrict__ dis, int n) {
    __shared__ int cnt[BROWS];
    int t = threadIdx.x, b = blockIdx.x;
    int r0 = b * BROWS;
    if (t < BROWS) cnt[t] = 0;
    __syncthreads();
    for (int i = part_off[b] + t; i < part_off[b + 1]; i += 256)
        atomicAdd(&cnt[part[i] >> 17], 1);
    __syncthreads();
    int nrows = min(BROWS, n - r0);
    if (t < nrows) {
        int dg = cnt[t];
        pdeg[r0 + t] = (dg + 3) & ~3;               // pad row segment to multiple of 4
        dis[r0 + t] = rsqrtf((float)(dg + 1));      // +1 self-loop
    }
}

// per-bucket CSR build: LDS row cursors + LDS staging, coalesced writeout. Pads -> col N_NODES.
__global__ __launch_bounds__(256) void build_csr(const unsigned* __restrict__ part,
                                                 const int* __restrict__ part_off,
                                                 const int* __restrict__ row_ptr,
                                                 int* __restrict__ cne, int n) {
    __shared__ int fill[BROWS];
    __shared__ int stage[CAP];
    int b = blockIdx.x;
    int r0 = b * BROWS;
    int t = threadIdx.x;
    int nrows = min(BROWS, n - r0);
    int base = row_ptr[r0];
    int region = row_ptr[r0 + nrows] - base;
    for (int r = t; r < nrows; r += 256) fill[r] = row_ptr[r0 + r] - base;
    int i0 = part_off[b], i1 = part_off[b + 1];
    if (region <= CAP) {
        for (int i = t; i < region; i += 256) stage[i] = N_NODES;
        __syncthreads();
        for (int i = i0 + t; i < i1; i += 256) {
            unsigned pe = part[i];
            int pos = atomicAdd(&fill[pe >> 17], 1);
            stage[pos] = (int)(pe & 0x1FFFFu);
        }
        __syncthreads();
        for (int i = t; i < region; i += 256) cne[base + i] = stage[i];
    } else {  // fallback (statistically unreachable)
        for (int i = t; i < region; i += 256) cne[base + i] = N_NODES;
        __syncthreads();
        for (int i = i0 + t; i < i1; i += 256) {
            unsigned pe = part[i];
            int pos = atomicAdd(&fill[pe >> 17], 1);
            cne[base + pos] = (int)(pe & 0x1FFFFu);
        }
    }
}

// ---------------- per-layer compute ----------------

__device__ __forceinline__ float bcast(float v, int lane) {
    return __uint_as_float(__builtin_amdgcn_readlane(__float_as_uint(v), lane));
}

// tmp2[row][lane] = dis[row] * sum_k X[row][k] * W[k][lane]; W in registers.
template <int K>
__global__ __launch_bounds__(256) void gemm_rows(const float* __restrict__ X,
                                                 const float* __restrict__ W,
                                                 const float* __restrict__ dis,
                                                 float* __restrict__ out, int n) {
    int wave = threadIdx.x >> 6, lane = threadIdx.x & 63;
    float w[K];
#pragma unroll
    for (int k = 0; k < K; k++) w[k] = W[k * HID + lane];
    int wpb = blockDim.x >> 6;
    int stride = gridDim.x * wpb;
    for (int row = blockIdx.x * wpb + wave; row < n; row += stride) {
        const float* xr = X + (size_t)row * K;
        float acc0 = 0.f, acc1 = 0.f;
        float xv0 = xr[lane];
        if constexpr (K == 128) {
            float xv1 = xr[lane + 64];
#pragma unroll
            for (int k = 0; k < 64; k += 2) {
                acc0 += bcast(xv0, k) * w[k];
                acc1 += bcast(xv0, k + 1) * w[k + 1];
            }
#pragma unroll
            for (int k = 0; k < 64; k += 2) {
                acc0 += bcast(xv1, k) * w[k + 64];
                acc1 += bcast(xv1, k + 1) * w[k + 65];
            }
        } else {
#pragma unroll
            for (int k = 0; k < 64; k += 2) {
                acc0 += bcast(xv0, k) * w[k];
                acc1 += bcast(xv0, k + 1) * w[k + 1];
            }
        }
        out[(size_t)row * HID + lane] = dis[row] * (acc0 + acc1);
    }
}

// out[row] = relu( dis[row] * (tmp2[row] + sum_cols tmp2[col]) + bias ); pads read zero row N.
__global__ __launch_bounds__(256) void aggregate(const float* __restrict__ tmp,
                                                 const float* __restrict__ dis,
                                                 const int* __restrict__ row_ptr,
                                                 const int* __restrict__ cne,
                                                 const float* __restrict__ bias,
                                                 float* __restrict__ out, int n) {
    int wave = threadIdx.x >> 6, lane = threadIdx.x & 63;
    int wpb = blockDim.x >> 6;
    int stride = gridDim.x * wpb;
    float bl = bias[lane];
    for (int row = blockIdx.x * wpb + wave; row < n; row += stride) {
        float dr = dis[row];
        float acc0 = tmp[(size_t)row * HID + lane];   // self-loop (tmp2 already has dis[src])
        float acc1 = 0.f, acc2 = 0.f, acc3 = 0.f;
        int s = row_ptr[row], e = row_ptr[row + 1];
        if (s < e) {
            int4 c = *(const int4*)(cne + s);
            float v0 = tmp[(size_t)c.x * HID + lane];
            float v1 = tmp[(size_t)c.y * HID + lane];
            float v2 = tmp[(size_t)c.z * HID + lane];
            float v3 = tmp[(size_t)c.w * HID + lane];
            for (int t = s + 4; t < e; t += 4) {
                int4 d4 = *(const int4*)(cne + t);
                float u0 = tmp[(size_t)d4.x * HID + lane];
                float u1 = tmp[(size_t)d4.y * HID + lane];
                float u2 = tmp[(size_t)d4.z * HID + lane];
                float u3 = tmp[(size_t)d4.w * HID + lane];
                acc0 += v0; acc1 += v1; acc2 += v2; acc3 += v3;
                c = d4;
                v0 = u0; v1 = u1; v2 = u2; v3 = u3;
            }
            acc0 += v0; acc1 += v1; acc2 += v2; acc3 += v3;
        }
        float r = dr * ((acc0 + acc1) + (acc2 + acc3)) + bl;
        out[(size_t)row * HID + lane] = fmaxf(r, 0.f);
    }
}

// one block (4 waves) per graph: mean+max pool, fused output dot
__global__ __launch_bounds__(256) void pool_kernel(const float* __restrict__ h,
                                                   const int* __restrict__ batch,
                                                   const float* __restrict__ Wout,
                                                   const float* __restrict__ bout,
                                                   float* __restrict__ d_out, int n) {
    __shared__ float ssum[4][64];
    __shared__ float smax[4][64];
    int g = blockIdx.x;
    int wave = threadIdx.x >> 6, j = threadIdx.x & 63;
    int lo = 0, hi = n;
    while (lo < hi) { int mid = (lo + hi) >> 1; if (batch[mid] < g) lo = mid + 1; else hi = mid; }
    int start = lo;
    hi = n;
    while (lo < hi) { int mid = (lo + hi) >> 1; if (batch[mid] < g + 1) lo = mid + 1; else hi = mid; }
    int end = lo;

    float sum = 0.f, mx = 0.f;   // h >= 0 post-relu; empty graph -> 0 per reference
    for (int i = start + wave; i < end; i += 4) {
        float v = h[(size_t)i * HID + j];
        sum += v;
        mx = fmaxf(mx, v);
    }
    ssum[wave][j] = sum;
    smax[wave][j] = mx;
    __syncthreads();
    if (wave == 0) {
        sum = (ssum[0][j] + ssum[1][j]) + (ssum[2][j] + ssum[3][j]);
        mx = fmaxf(fmaxf(smax[0][j], smax[1][j]), fmaxf(smax[2][j], smax[3][j]));
        float cnt = (float)(end - start);
        float mean = sum / fmaxf(cnt, 1.f);
        float* pooled = d_out + NUM_GRAPHS;
        pooled[(size_t)g * (2 * HID) + j] = mean;
        pooled[(size_t)g * (2 * HID) + HID + j] = mx;
        float c = mean * Wout[j] + mx * Wout[HID + j];
#pragma unroll
        for (int off = 32; off; off >>= 1) c += __shfl_down(c, off);
        if (j == 0) d_out[g] = c + bout[0];
    }
}

// ---------------- launch ----------------

extern "C" void kernel_launch(void* const* d_in, const int* in_sizes, int n_in,
                              void* d_out, int out_size, void* d_ws, size_t ws_size,
                              hipStream_t stream) {
    const float* x    = (const float*)d_in[0];
    const int*   edge = (const int*)d_in[1];
    const int*   batch= (const int*)d_in[2];
    const float* W1 = (const float*)d_in[3];  const float* b1 = (const float*)d_in[4];
    const float* W2 = (const float*)d_in[5];  const float* b2 = (const float*)d_in[6];
    const float* W3 = (const float*)d_in[7];  const float* b3 = (const float*)d_in[8];
    const float* W4 = (const float*)d_in[9];  const float* b4 = (const float*)d_in[10];
    const float* Wout = (const float*)d_in[11]; const float* bout = (const float*)d_in[12];
    float* out = (float*)d_out;

    const int N = N_NODES;
    const int E = in_sizes[1] / 2;
    const int* src = edge;
    const int* dst = edge + E;
    const int chunk = (E + NCHUNK - 1) / NCHUNK;

    char* p = (char*)d_ws;
    auto alloc = [&](size_t bytes) -> char* {
        char* r = p;
        p += (bytes + 255) & ~(size_t)255;
        return r;
    };
    int*      pdeg     = (int*)alloc((size_t)N * 4);
    int*      row_ptr  = (int*)alloc((size_t)(N + 1) * 4);
    int*      partial  = (int*)alloc((size_t)TOTP * 4);
    int*      pincl    = (int*)alloc((size_t)TOTP * 4);
    int*      pbase    = (int*)alloc((size_t)TOTP * 4);
    int*      part_off = (int*)alloc((size_t)(NBUCK + 1) * 4);
    unsigned* part     = (unsigned*)alloc((size_t)1600000 * 4);
    int*      cne      = (int*)alloc((size_t)CNE_MAX * 4);
    float*    dis      = (float*)alloc((size_t)N * 4);
    int*      bsum     = (int*)alloc(128 * 4);
    int*      boff     = (int*)alloc(128 * 4);
    float*    tmp      = (float*)alloc((size_t)(N + 1) * HID * 4);
    float*    hA       = (float*)alloc((size_t)(N + 1) * HID * 4);

    hipMemsetAsync(tmp + (size_t)N * HID, 0, HID * 4, stream);   // zero row N (pad target)
    hipMemsetAsync(hA + (size_t)N * HID, 0, HID * 4, stream);

    hist_partial<<<NCHUNK, 256, 0, stream>>>(dst, partial, E, chunk);
    // hierarchical exclusive scan of partial[TOTP]
    int nbp = (TOTP + 1023) / 1024;  // 98
    scan1<<<nbp, 256, 0, stream>>>(partial, pincl, bsum, TOTP);
    scan2<<<1, 128, 0, stream>>>(bsum, boff, nbp);
    scan3p<<<(TOTP + 255) / 256, 256, 0, stream>>>(partial, pincl, boff, pbase, part_off, E);
    partition_edges<<<NCHUNK, 256, 0, stream>>>(src, dst, pbase, part, E, chunk);
    deg_dis<<<NBUCK, 256, 0, stream>>>(part, part_off, pdeg, dis, N);

    int nb = (N + 1023) / 1024;  // 98
    scan1<<<nb, 256, 0, stream>>>(pdeg, row_ptr + 1, bsum, N);
    scan2<<<1, 128, 0, stream>>>(bsum, boff, nb);
    scan3<<<(N + 255) / 256, 256, 0, stream>>>(row_ptr, boff, N);
    build_csr<<<NBUCK, 256, 0, stream>>>(part, part_off, row_ptr, cne, N);

    const int AGG_BLOCKS = 2048;

    gemm_rows<IN_DIM><<<1024, 256, 0, stream>>>(x, W1, dis, tmp, N);
    aggregate<<<AGG_BLOCKS, 256, 0, stream>>>(tmp, dis, row_ptr, cne, b1, hA, N);
    gemm_rows<HID><<<2048, 256, 0, stream>>>(hA, W2, dis, tmp, N);
    aggregate<<<AGG_BLOCKS, 256, 0, stream>>>(tmp, dis, row_ptr, cne, b2, hA, N);
    gemm_rows<HID><<<2048, 256, 0, stream>>>(hA, W3, dis, tmp, N);
    aggregate<<<AGG_BLOCKS, 256, 0, stream>>>(tmp, dis, row_ptr, cne, b3, hA, N);
    gemm_rows<HID><<<2048, 256, 0, stream>>>(hA, W4, dis, tmp, N);
    aggregate<<<AGG_BLOCKS, 256, 0, stream>>>(tmp, dis, row_ptr, cne, b4, hA, N);

    pool_kernel<<<NUM_GRAPHS, 256, 0, stream>>>(hA, batch, Wout, bout, out, N);
}

// Round 6
// 502.065 us; speedup vs baseline: 1.5028x; 1.1183x over previous
//
#include <hip/hip_runtime.h>
#include <hip/hip_fp16.h>

#define N_NODES 100000
#define IN_DIM 128
#define HID 64
#define NUM_GRAPHS 2048
#define CNE_MAX (1600000 + 3 * N_NODES)   // padded-to-4 CSR upper bound
#define BROWS 128                          // rows per bucket
#define NBUCK ((N_NODES + BROWS - 1) / BROWS)   // 782
#define NCHUNK 128                         // edge chunks (one block each)
#define TOTP (NBUCK * NCHUNK)              // 100096 partial counters
#define CAP 4096                           // LDS staging entries per bucket (mean ~2240)

// ---------------- build phase (NO per-edge global atomics anywhere) ----------------

// per-chunk bucket histogram in LDS -> partial[bucket][chunk] (bucket-major)
__global__ __launch_bounds__(256) void hist_partial(const int* __restrict__ dst,
                                                    int* __restrict__ partial,
                                                    int E, int chunk) {
    __shared__ int lh[NBUCK];
    int t = threadIdx.x, c = blockIdx.x;
    for (int b = t; b < NBUCK; b += 256) lh[b] = 0;
    __syncthreads();
    int lo = c * chunk, hi = min(lo + chunk, E);
    for (int i = lo + t; i < hi; i += 256) atomicAdd(&lh[dst[i] >> 7], 1);
    __syncthreads();
    for (int b = t; b < NBUCK; b += 256) partial[b * NCHUNK + c] = lh[b];
}

// generic hierarchical scan, phase 1: per-block (1024 elems) inclusive scan + block sums
__global__ void scan1(const int* __restrict__ counts, int* __restrict__ out1,
                      int* __restrict__ bsum, int n) {
    __shared__ int s[256];
    int t = threadIdx.x;
    int base = blockIdx.x * 1024 + t * 4;
    int v[4];
#pragma unroll
    for (int i = 0; i < 4; i++) v[i] = (base + i < n) ? counts[base + i] : 0;
    int tsum = v[0] + v[1] + v[2] + v[3];
    s[t] = tsum;
    __syncthreads();
    for (int off = 1; off < 256; off <<= 1) {
        int tv = (t >= off) ? s[t - off] : 0;
        __syncthreads();
        s[t] += tv;
        __syncthreads();
    }
    int excl = s[t] - tsum;
    if (t == 255) bsum[blockIdx.x] = s[255];
    int run = excl;
#pragma unroll
    for (int i = 0; i < 4; i++) {
        run += v[i];
        if (base + i < n) out1[base + i] = run;
    }
}

// phase 2: exclusive scan of block sums (nb <= 128)
__global__ void scan2(const int* __restrict__ bsum, int* __restrict__ boff, int nb) {
    __shared__ int s[128];
    int t = threadIdx.x;
    int v = (t < nb) ? bsum[t] : 0;
    s[t] = v;
    __syncthreads();
    for (int off = 1; off < 128; off <<= 1) {
        int tv = (t >= off) ? s[t - off] : 0;
        __syncthreads();
        s[t] += tv;
        __syncthreads();
    }
    if (t < nb) boff[t] = s[t] - v;
}

// phase 3 for row_ptr: add block offsets in place
__global__ void scan3(int* __restrict__ row_ptr, const int* __restrict__ boff, int n) {
    int i = blockIdx.x * blockDim.x + threadIdx.x;
    if (i == 0) row_ptr[0] = 0;
    if (i < n) row_ptr[i + 1] += boff[i >> 10];
}

// phase 3 for partial: exclusive = inclusive - self + block_off; emit part_off per bucket
__global__ void scan3p(const int* __restrict__ partial, const int* __restrict__ pincl,
                       const int* __restrict__ boff, int* __restrict__ base,
                       int* __restrict__ part_off, int E) {
    int i = blockIdx.x * blockDim.x + threadIdx.x;
    if (i < TOTP) {
        int v = pincl[i] + boff[i >> 10] - partial[i];
        base[i] = v;
        if ((i & (NCHUNK - 1)) == 0) part_off[i / NCHUNK] = v;
    }
    if (i == 0) part_off[NBUCK] = E;
}

// stable partition: each chunk re-reads its edges, takes positions from LDS cursors
__global__ __launch_bounds__(256) void partition_edges(const int* __restrict__ src,
                                                       const int* __restrict__ dst,
                                                       const int* __restrict__ base,
                                                       unsigned* __restrict__ part,
                                                       int E, int chunk) {
    __shared__ int cur[NBUCK];
    int t = threadIdx.x, c = blockIdx.x;
    for (int b = t; b < NBUCK; b += 256) cur[b] = base[b * NCHUNK + c];
    __syncthreads();
    int lo = c * chunk, hi = min(lo + chunk, E);
    for (int i = lo + t; i < hi; i += 256) {
        int s = src[i], d = dst[i];
        int pos = atomicAdd(&cur[d >> 7], 1);
        part[pos] = (unsigned)s | ((unsigned)(d & (BROWS - 1)) << 17);
    }
}

// per-bucket local-row counts from the strip -> padded degree + dis, coalesced writes
__global__ __launch_bounds__(256) void deg_dis(const unsigned* __restrict__ part,
                                               const int* __restrict__ part_off,
                                               int* __restrict__ pdeg,
                                               float* __restrict__ dis, int n) {
    __shared__ int cnt[BROWS];
    int t = threadIdx.x, b = blockIdx.x;
    int r0 = b * BROWS;
    if (t < BROWS) cnt[t] = 0;
    __syncthreads();
    for (int i = part_off[b] + t; i < part_off[b + 1]; i += 256)
        atomicAdd(&cnt[part[i] >> 17], 1);
    __syncthreads();
    int nrows = min(BROWS, n - r0);
    if (t < nrows) {
        int dg = cnt[t];
        pdeg[r0 + t] = (dg + 3) & ~3;               // pad row segment to multiple of 4
        dis[r0 + t] = rsqrtf((float)(dg + 1));      // +1 self-loop
    }
}

// per-bucket CSR build: LDS row cursors + LDS staging, coalesced writeout. Pads -> col N_NODES.
__global__ __launch_bounds__(256) void build_csr(const unsigned* __restrict__ part,
                                                 const int* __restrict__ part_off,
                                                 const int* __restrict__ row_ptr,
                                                 int* __restrict__ cne, int n) {
    __shared__ int fill[BROWS];
    __shared__ int stage[CAP];
    int b = blockIdx.x;
    int r0 = b * BROWS;
    int t = threadIdx.x;
    int nrows = min(BROWS, n - r0);
    int base = row_ptr[r0];
    int region = row_ptr[r0 + nrows] - base;
    for (int r = t; r < nrows; r += 256) fill[r] = row_ptr[r0 + r] - base;
    int i0 = part_off[b], i1 = part_off[b + 1];
    if (region <= CAP) {
        for (int i = t; i < region; i += 256) stage[i] = N_NODES;
        __syncthreads();
        for (int i = i0 + t; i < i1; i += 256) {
            unsigned pe = part[i];
            int pos = atomicAdd(&fill[pe >> 17], 1);
            stage[pos] = (int)(pe & 0x1FFFFu);
        }
        __syncthreads();
        for (int i = t; i < region; i += 256) cne[base + i] = stage[i];
    } else {  // fallback (statistically unreachable)
        for (int i = t; i < region; i += 256) cne[base + i] = N_NODES;
        __syncthreads();
        for (int i = i0 + t; i < i1; i += 256) {
            unsigned pe = part[i];
            int pos = atomicAdd(&fill[pe >> 17], 1);
            cne[base + pos] = (int)(pe & 0x1FFFFu);
        }
    }
}

// ---------------- per-layer compute ----------------

__device__ __forceinline__ float bcast(float v, int lane) {
    return __uint_as_float(__builtin_amdgcn_readlane(__float_as_uint(v), lane));
}

// tmp2[row][lane] = (half) dis[row] * sum_k X[row][k] * W[k][lane]; W in registers.
template <int K>
__global__ __launch_bounds__(256) void gemm_rows(const float* __restrict__ X,
                                                 const float* __restrict__ W,
                                                 const float* __restrict__ dis,
                                                 __half* __restrict__ out, int n) {
    int wave = threadIdx.x >> 6, lane = threadIdx.x & 63;
    float w[K];
#pragma unroll
    for (int k = 0; k < K; k++) w[k] = W[k * HID + lane];
    int wpb = blockDim.x >> 6;
    int stride = gridDim.x * wpb;
    for (int row = blockIdx.x * wpb + wave; row < n; row += stride) {
        const float* xr = X + (size_t)row * K;
        float acc0 = 0.f, acc1 = 0.f;
        float xv0 = xr[lane];
        if constexpr (K == 128) {
            float xv1 = xr[lane + 64];
#pragma unroll
            for (int k = 0; k < 64; k += 2) {
                acc0 += bcast(xv0, k) * w[k];
                acc1 += bcast(xv0, k + 1) * w[k + 1];
            }
#pragma unroll
            for (int k = 0; k < 64; k += 2) {
                acc0 += bcast(xv1, k) * w[k + 64];
                acc1 += bcast(xv1, k + 1) * w[k + 65];
            }
        } else {
#pragma unroll
            for (int k = 0; k < 64; k += 2) {
                acc0 += bcast(xv0, k) * w[k];
                acc1 += bcast(xv0, k + 1) * w[k + 1];
            }
        }
        out[row * HID + lane] = __float2half(dis[row] * (acc0 + acc1));
    }
}

// out[row] = relu( dis[row] * (tmp2[row] + sum_cols tmp2[col]) + bias ); pads read zero row N.
// tmp2 is fp16: each row gather is 128 B (64 lanes x 2 B), halving L2-miss bytes.
__global__ __launch_bounds__(256) void aggregate(const __half* __restrict__ tmp,
                                                 const float* __restrict__ dis,
                                                 const int* __restrict__ row_ptr,
                                                 const int* __restrict__ cne,
                                                 const float* __restrict__ bias,
                                                 float* __restrict__ out, int n) {
    int wave = threadIdx.x >> 6, lane = threadIdx.x & 63;
    int wpb = blockDim.x >> 6;
    int stride = gridDim.x * wpb;
    float bl = bias[lane];
    for (int row = blockIdx.x * wpb + wave; row < n; row += stride) {
        float dr = dis[row];
        float acc0 = __half2float(tmp[row * HID + lane]);   // self-loop
        float acc1 = 0.f, acc2 = 0.f, acc3 = 0.f;
        int s = row_ptr[row], e = row_ptr[row + 1];
        if (s < e) {
            int4 c = *(const int4*)(cne + s);
            float v0 = __half2float(tmp[c.x * HID + lane]);
            float v1 = __half2float(tmp[c.y * HID + lane]);
            float v2 = __half2float(tmp[c.z * HID + lane]);
            float v3 = __half2float(tmp[c.w * HID + lane]);
            for (int t = s + 4; t < e; t += 4) {
                int4 d4 = *(const int4*)(cne + t);
                float u0 = __half2float(tmp[d4.x * HID + lane]);
                float u1 = __half2float(tmp[d4.y * HID + lane]);
                float u2 = __half2float(tmp[d4.z * HID + lane]);
                float u3 = __half2float(tmp[d4.w * HID + lane]);
                acc0 += v0; acc1 += v1; acc2 += v2; acc3 += v3;
                c = d4;
                v0 = u0; v1 = u1; v2 = u2; v3 = u3;
            }
            acc0 += v0; acc1 += v1; acc2 += v2; acc3 += v3;
        }
        float r = dr * ((acc0 + acc1) + (acc2 + acc3)) + bl;
        out[row * HID + lane] = fmaxf(r, 0.f);
    }
}

// one block (4 waves) per graph: mean+max pool, fused output dot
__global__ __launch_bounds__(256) void pool_kernel(const float* __restrict__ h,
                                                   const int* __restrict__ batch,
                                                   const float* __restrict__ Wout,
                                                   const float* __restrict__ bout,
                                                   float* __restrict__ d_out, int n) {
    __shared__ float ssum[4][64];
    __shared__ float smax[4][64];
    int g = blockIdx.x;
    int wave = threadIdx.x >> 6, j = threadIdx.x & 63;
    int lo = 0, hi = n;
    while (lo < hi) { int mid = (lo + hi) >> 1; if (batch[mid] < g) lo = mid + 1; else hi = mid; }
    int start = lo;
    hi = n;
    while (lo < hi) { int mid = (lo + hi) >> 1; if (batch[mid] < g + 1) lo = mid + 1; else hi = mid; }
    int end = lo;

    float sum = 0.f, mx = 0.f;   // h >= 0 post-relu; empty graph -> 0 per reference
    for (int i = start + wave; i < end; i += 4) {
        float v = h[(size_t)i * HID + j];
        sum += v;
        mx = fmaxf(mx, v);
    }
    ssum[wave][j] = sum;
    smax[wave][j] = mx;
    __syncthreads();
    if (wave == 0) {
        sum = (ssum[0][j] + ssum[1][j]) + (ssum[2][j] + ssum[3][j]);
        mx = fmaxf(fmaxf(smax[0][j], smax[1][j]), fmaxf(smax[2][j], smax[3][j]));
        float cnt = (float)(end - start);
        float mean = sum / fmaxf(cnt, 1.f);
        float* pooled = d_out + NUM_GRAPHS;
        pooled[(size_t)g * (2 * HID) + j] = mean;
        pooled[(size_t)g * (2 * HID) + HID + j] = mx;
        float c = mean * Wout[j] + mx * Wout[HID + j];
#pragma unroll
        for (int off = 32; off; off >>= 1) c += __shfl_down(c, off);
        if (j == 0) d_out[g] = c + bout[0];
    }
}

// ---------------- launch ----------------

extern "C" void kernel_launch(void* const* d_in, const int* in_sizes, int n_in,
                              void* d_out, int out_size, void* d_ws, size_t ws_size,
                              hipStream_t stream) {
    const float* x    = (const float*)d_in[0];
    const int*   edge = (const int*)d_in[1];
    const int*   batch= (const int*)d_in[2];
    const float* W1 = (const float*)d_in[3];  const float* b1 = (const float*)d_in[4];
    const float* W2 = (const float*)d_in[5];  const float* b2 = (const float*)d_in[6];
    const float* W3 = (const float*)d_in[7];  const float* b3 = (const float*)d_in[8];
    const float* W4 = (const float*)d_in[9];  const float* b4 = (const float*)d_in[10];
    const float* Wout = (const float*)d_in[11]; const float* bout = (const float*)d_in[12];
    float* out = (float*)d_out;

    const int N = N_NODES;
    const int E = in_sizes[1] / 2;
    const int* src = edge;
    const int* dst = edge + E;
    const int chunk = (E + NCHUNK - 1) / NCHUNK;

    char* p = (char*)d_ws;
    auto alloc = [&](size_t bytes) -> char* {
        char* r = p;
        p += (bytes + 255) & ~(size_t)255;
        return r;
    };
    int*      pdeg     = (int*)alloc((size_t)N * 4);
    int*      row_ptr  = (int*)alloc((size_t)(N + 1) * 4);
    int*      partial  = (int*)alloc((size_t)TOTP * 4);
    int*      pincl    = (int*)alloc((size_t)TOTP * 4);
    int*      pbase    = (int*)alloc((size_t)TOTP * 4);
    int*      part_off = (int*)alloc((size_t)(NBUCK + 1) * 4);
    unsigned* part     = (unsigned*)alloc((size_t)1600000 * 4);
    int*      cne      = (int*)alloc((size_t)CNE_MAX * 4);
    float*    dis      = (float*)alloc((size_t)N * 4);
    int*      bsum     = (int*)alloc(128 * 4);
    int*      boff     = (int*)alloc(128 * 4);
    __half*   tmp      = (__half*)alloc((size_t)(N + 1) * HID * 2);
    float*    hA       = (float*)alloc((size_t)N * HID * 4);

    hipMemsetAsync(tmp + (size_t)N * HID, 0, HID * 2, stream);   // zero row N (pad target)

    hist_partial<<<NCHUNK, 256, 0, stream>>>(dst, partial, E, chunk);
    // hierarchical exclusive scan of partial[TOTP]
    int nbp = (TOTP + 1023) / 1024;  // 98
    scan1<<<nbp, 256, 0, stream>>>(partial, pincl, bsum, TOTP);
    scan2<<<1, 128, 0, stream>>>(bsum, boff, nbp);
    scan3p<<<(TOTP + 255) / 256, 256, 0, stream>>>(partial, pincl, boff, pbase, part_off, E);
    partition_edges<<<NCHUNK, 256, 0, stream>>>(src, dst, pbase, part, E, chunk);
    deg_dis<<<NBUCK, 256, 0, stream>>>(part, part_off, pdeg, dis, N);

    int nb = (N + 1023) / 1024;  // 98
    scan1<<<nb, 256, 0, stream>>>(pdeg, row_ptr + 1, bsum, N);
    scan2<<<1, 128, 0, stream>>>(bsum, boff, nb);
    scan3<<<(N + 255) / 256, 256, 0, stream>>>(row_ptr, boff, N);
    build_csr<<<NBUCK, 256, 0, stream>>>(part, part_off, row_ptr, cne, N);

    const int AGG_BLOCKS = 2048;

    gemm_rows<IN_DIM><<<1024, 256, 0, stream>>>(x, W1, dis, tmp, N);
    aggregate<<<AGG_BLOCKS, 256, 0, stream>>>(tmp, dis, row_ptr, cne, b1, hA, N);
    gemm_rows<HID><<<2048, 256, 0, stream>>>(hA, W2, dis, tmp, N);
    aggregate<<<AGG_BLOCKS, 256, 0, stream>>>(tmp, dis, row_ptr, cne, b2, hA, N);
    gemm_rows<HID><<<2048, 256, 0, stream>>>(hA, W3, dis, tmp, N);
    aggregate<<<AGG_BLOCKS, 256, 0, stream>>>(tmp, dis, row_ptr, cne, b3, hA, N);
    gemm_rows<HID><<<2048, 256, 0, stream>>>(hA, W4, dis, tmp, N);
    aggregate<<<AGG_BLOCKS, 256, 0, stream>>>(tmp, dis, row_ptr, cne, b4, hA, N);

    pool_kernel<<<NUM_GRAPHS, 256, 0, stream>>>(hA, batch, Wout, bout, out, N);
}